// Round 11
// baseline (1110.164 us; speedup 1.0000x reference)
//
#include <hip/hip_runtime.h>
#include <stdint.h>

typedef __bf16 bf16;
typedef __bf16 bf16x8 __attribute__((ext_vector_type(8)));
typedef __bf16 bf16x4 __attribute__((ext_vector_type(4)));
typedef float f32x4 __attribute__((ext_vector_type(4)));

#define DEV __device__ __forceinline__

static constexpr int Dm   = 1024;
static constexpr int DFFm = 4096;
static constexpr int Tm   = 2048;   // B*S tokens
static constexpr int Vm   = 32000;
static constexpr float TAU = 0.04f; // router margin gate (err max ~9e-3)

// ---------------- helpers ----------------
#define GLOAD_LDS16(g, l)                                                      \
  __builtin_amdgcn_global_load_lds(                                            \
      (const __attribute__((address_space(1))) unsigned int*)(g),              \
      (__attribute__((address_space(3))) unsigned int*)(l), 16, 0, 0)

DEV float gelu_tanh(float v) {  // matches jax.nn.gelu (approximate=True)
  float u = 0.7978845608028654f * (v + 0.044715f * v * v * v);
  float e = __expf(2.0f * u);
  float t = 1.0f - 2.0f / (e + 1.0f);
  return 0.5f * v * (1.0f + t);
}

// =======================================================================
// 256^2 / 8-wave / 8-phase GEMM (logits) — R7/R8 verified, unchanged.
// =======================================================================
template <bool SWZ>
__launch_bounds__(512, 2)
__global__ void gemm256_8p(const bf16* __restrict__ A, const bf16* __restrict__ B,
                           const float* __restrict__ bias, float* __restrict__ out,
                           int Kc, int Nc) {
  __shared__ bf16 lds[65536];
  const int tid  = threadIdx.x;
  const int lane = tid & 63;
  const int wid  = tid >> 6;
  const int wr   = wid >> 2;
  const int wc   = wid & 3;

  int bx = blockIdx.x, by = blockIdx.y;
  if constexpr (SWZ) {
    const int gx = gridDim.x, gy = gridDim.y;
    const int nwg = gx * gy;
    const int lin = by * gx + bx;
    const int q = nwg >> 3, r = nwg & 7;
    const int xcd = lin & 7, loc = lin >> 3;
    const int nid = (xcd < r ? xcd * (q + 1) : r * (q + 1) + (xcd - r) * q) + loc;
    bx = nid / gy; by = nid % gy;
  }
  const long am0 = (long)by * 256;
  const long bn0 = (long)bx * 256;
  const long K = Kc;
  const int NT = Kc >> 6;

  const int sub = (lane & 7) ^ (lane >> 3);
  const int rw  = wid * 8 + (lane >> 3);
  const bf16 *aS[4], *bS[4];
#pragma unroll
  for (int j = 0; j < 4; ++j) {
    aS[j] = A + (am0 + j * 64 + rw) * K + sub * 8;
    bS[j] = B + (bn0 + j * 64 + rw) * K + sub * 8;
  }
  char* ldsc = (char*)(void*)lds;

#define STG_A(kt, j)                                                           \
  GLOAD_LDS16(aS[j] + (long)(kt) * 64,                                         \
              ldsc + ((kt) & 1) * 65536 + ((j) * 64 + wid * 8) * 128)
#define STG_B(kt, j)                                                           \
  GLOAD_LDS16(bS[j] + (long)(kt) * 64,                                         \
              ldsc + ((kt) & 1) * 65536 + 32768 + ((j) * 64 + wid * 8) * 128)

  STG_B(0, 0); STG_B(0, 1); STG_B(0, 2); STG_B(0, 3);
  STG_A(0, 0); STG_A(0, 2); STG_A(0, 1); STG_A(0, 3);
  if (NT > 1) {
    STG_B(1, 0); STG_B(1, 1); STG_B(1, 2); STG_B(1, 3);
    STG_A(1, 0); STG_A(1, 2);
    asm volatile("s_waitcnt vmcnt(6)" ::: "memory");
  } else {
    asm volatile("s_waitcnt vmcnt(0)" ::: "memory");
  }
  __builtin_amdgcn_s_barrier();

  f32x4 acc[8][4] = {};
  const int r15 = lane & 15;
  const int kcs = lane >> 4;
  const int x7  = lane & 7;
  const int q80 = (kcs ^ x7) << 3;
  const int q81 = ((kcs + 4) ^ x7) << 3;

  for (int t = 0; t < NT; ++t) {
    const bf16* LAb = lds + (t & 1) * 32768 + wr * 128 * 64;
    const bf16* LBb = lds + (t & 1) * 32768 + 16384 + wc * 64 * 64;
    bf16x8 b0[4], b1[4];

    {
      bf16x8 a0, a1, a2, a3;
#pragma unroll
      for (int n = 0; n < 4; ++n) {
        b0[n] = *(const bf16x8*)(LBb + (n * 16 + r15) * 64 + q80);
        b1[n] = *(const bf16x8*)(LBb + (n * 16 + r15) * 64 + q81);
      }
      a0 = *(const bf16x8*)(LAb + (0 * 16 + r15) * 64 + q80);
      a1 = *(const bf16x8*)(LAb + (0 * 16 + r15) * 64 + q81);
      a2 = *(const bf16x8*)(LAb + (1 * 16 + r15) * 64 + q80);
      a3 = *(const bf16x8*)(LAb + (1 * 16 + r15) * 64 + q81);
      if (t + 1 < NT) { STG_A(t + 1, 1); STG_A(t + 1, 3); }
      __builtin_amdgcn_s_barrier();
      asm volatile("s_waitcnt lgkmcnt(0)" ::: "memory");
      __builtin_amdgcn_s_setprio(1);
#pragma unroll
      for (int n = 0; n < 4; ++n) {
        acc[0][n] = __builtin_amdgcn_mfma_f32_16x16x32_bf16(a0, b0[n], acc[0][n], 0, 0, 0);
        acc[0][n] = __builtin_amdgcn_mfma_f32_16x16x32_bf16(a1, b1[n], acc[0][n], 0, 0, 0);
        acc[1][n] = __builtin_amdgcn_mfma_f32_16x16x32_bf16(a2, b0[n], acc[1][n], 0, 0, 0);
        acc[1][n] = __builtin_amdgcn_mfma_f32_16x16x32_bf16(a3, b1[n], acc[1][n], 0, 0, 0);
      }
      __builtin_amdgcn_s_setprio(0);
      __builtin_amdgcn_s_barrier();
    }
    {
      bf16x8 a0, a1, a2, a3;
      a0 = *(const bf16x8*)(LAb + (2 * 16 + r15) * 64 + q80);
      a1 = *(const bf16x8*)(LAb + (2 * 16 + r15) * 64 + q81);
      a2 = *(const bf16x8*)(LAb + (3 * 16 + r15) * 64 + q80);
      a3 = *(const bf16x8*)(LAb + (3 * 16 + r15) * 64 + q81);
      if (t + 2 < NT) { STG_B(t + 2, 0); STG_B(t + 2, 1); }
      __builtin_amdgcn_s_barrier();
      asm volatile("s_waitcnt lgkmcnt(0)" ::: "memory");
      __builtin_amdgcn_s_setprio(1);
#pragma unroll
      for (int n = 0; n < 4; ++n) {
        acc[2][n] = __builtin_amdgcn_mfma_f32_16x16x32_bf16(a0, b0[n], acc[2][n], 0, 0, 0);
        acc[2][n] = __builtin_amdgcn_mfma_f32_16x16x32_bf16(a1, b1[n], acc[2][n], 0, 0, 0);
        acc[3][n] = __builtin_amdgcn_mfma_f32_16x16x32_bf16(a2, b0[n], acc[3][n], 0, 0, 0);
        acc[3][n] = __builtin_amdgcn_mfma_f32_16x16x32_bf16(a3, b1[n], acc[3][n], 0, 0, 0);
      }
      __builtin_amdgcn_s_setprio(0);
      __builtin_amdgcn_s_barrier();
    }
    {
      bf16x8 a0, a1, a2, a3;
      a0 = *(const bf16x8*)(LAb + (4 * 16 + r15) * 64 + q80);
      a1 = *(const bf16x8*)(LAb + (4 * 16 + r15) * 64 + q81);
      a2 = *(const bf16x8*)(LAb + (5 * 16 + r15) * 64 + q80);
      a3 = *(const bf16x8*)(LAb + (5 * 16 + r15) * 64 + q81);
      if (t + 2 < NT) { STG_B(t + 2, 2); STG_B(t + 2, 3); }
      __builtin_amdgcn_s_barrier();
      asm volatile("s_waitcnt lgkmcnt(0)" ::: "memory");
      __builtin_amdgcn_s_setprio(1);
#pragma unroll
      for (int n = 0; n < 4; ++n) {
        acc[4][n] = __builtin_amdgcn_mfma_f32_16x16x32_bf16(a0, b0[n], acc[4][n], 0, 0, 0);
        acc[4][n] = __builtin_amdgcn_mfma_f32_16x16x32_bf16(a1, b1[n], acc[4][n], 0, 0, 0);
        acc[5][n] = __builtin_amdgcn_mfma_f32_16x16x32_bf16(a2, b0[n], acc[5][n], 0, 0, 0);
        acc[5][n] = __builtin_amdgcn_mfma_f32_16x16x32_bf16(a3, b1[n], acc[5][n], 0, 0, 0);
      }
      __builtin_amdgcn_s_setprio(0);
      __builtin_amdgcn_s_barrier();
    }
    {
      bf16x8 a0, a1, a2, a3;
      a0 = *(const bf16x8*)(LAb + (6 * 16 + r15) * 64 + q80);
      a1 = *(const bf16x8*)(LAb + (6 * 16 + r15) * 64 + q81);
      a2 = *(const bf16x8*)(LAb + (7 * 16 + r15) * 64 + q80);
      a3 = *(const bf16x8*)(LAb + (7 * 16 + r15) * 64 + q81);
      if (t + 2 < NT) {
        STG_A(t + 2, 0); STG_A(t + 2, 2);
        asm volatile("s_waitcnt vmcnt(6)" ::: "memory");
      } else if (t + 1 < NT) {
        asm volatile("s_waitcnt vmcnt(0)" ::: "memory");
      }
      __builtin_amdgcn_s_barrier();
      asm volatile("s_waitcnt lgkmcnt(0)" ::: "memory");
      __builtin_amdgcn_s_setprio(1);
#pragma unroll
      for (int n = 0; n < 4; ++n) {
        acc[6][n] = __builtin_amdgcn_mfma_f32_16x16x32_bf16(a0, b0[n], acc[6][n], 0, 0, 0);
        acc[6][n] = __builtin_amdgcn_mfma_f32_16x16x32_bf16(a1, b1[n], acc[6][n], 0, 0, 0);
        acc[7][n] = __builtin_amdgcn_mfma_f32_16x16x32_bf16(a2, b0[n], acc[7][n], 0, 0, 0);
        acc[7][n] = __builtin_amdgcn_mfma_f32_16x16x32_bf16(a3, b1[n], acc[7][n], 0, 0, 0);
      }
      __builtin_amdgcn_s_setprio(0);
      __builtin_amdgcn_s_barrier();
    }
  }
#undef STG_A
#undef STG_B

  const long N = Nc;
#pragma unroll
  for (int m = 0; m < 8; ++m) {
#pragma unroll
    for (int n = 0; n < 4; ++n) {
      const long col = bn0 + wc * 64 + n * 16 + r15;
      const float bv = bias[col];
#pragma unroll
      for (int r = 0; r < 4; ++r) {
        const long row = am0 + wr * 128 + m * 16 + (lane >> 4) * 4 + r;
        out[row * N + col] = acc[m][n][r] + bv;
      }
    }
  }
}

// ---------------- 128^2 GEMM (R8 verified structure, BK=64, 2-phase) -------
// Adds: runtime cnt-based M-exit for compact pass-2 dispatches (p.cnt set,
// GATHER=false) + row<cntE guards on GELU_SPLIT/RESID epilogues.
enum { EPI_GELU_SPLIT = 0, EPI_RESID = 1, EPI_GELU_BF16 = 2, EPI_MOE = 3 };

struct GemmP {
  const bf16* Ah;
  const bf16* Bh;
  const float* bias;
  const float* rwp;     // routing weights [T][8]
  const int* cnt;       // expert counts [8] (GATHER/MOE) or row count [1]
  const int* idx;       // per-expert token lists [8][2048]
  float* outF;
  bf16* outH;
  int K; int N;
  int lda; int ldb; int ldo;
  long aBS, bBS, outBS;        // per-ze strides
  int biasBS;
  int ebase;                   // global expert base for ze=0
  int kcShift; int kcK;        // split-K: z = (ze << kcShift) | kc
  int aT, aS2, bT, bS2;        // k-wrap remap (0 => identity)
};

template <int EPI, bool GATHER, bool SWZ>
__launch_bounds__(256, 2)
__global__ void gemm_bt(GemmP p) {
  __shared__ bf16 lds[16384];          // A[128][64] | B[128][64], 32 KiB
  bf16* ldsA = lds;
  bf16* ldsB = lds + 8192;

  const int tid  = threadIdx.x;
  const int lane = tid & 63;
  const int wid  = tid >> 6;
  const int wr   = wid >> 1;
  const int wc   = wid & 1;
  const int z    = blockIdx.z;
  const int kc   = z & ((1 << p.kcShift) - 1);
  const int ze   = z >> p.kcShift;

  int bx = blockIdx.x, by = blockIdx.y;
  if constexpr (SWZ) {
    const int gx = gridDim.x, gy = gridDim.y;
    const int nwg = gx * gy;
    const int lin = by * gx + bx;
    const int q = nwg >> 3, r = nwg & 7;
    const int xcd = lin & 7, loc = lin >> 3;
    const int nid = (xcd < r ? xcd * (q + 1) : r * (q + 1) + (xcd - r) * q) + loc;
    bx = nid / gy; by = nid % gy;
  }

  const long am0 = (long)by * 128;
  const long bn0 = (long)bx * 128;

  int cntE = 1 << 30;
  const int* il = nullptr;
  if constexpr (GATHER || EPI == EPI_MOE) {
    cntE = p.cnt[p.ebase + ze];
    if (am0 >= cntE) return;  // wave-uniform early exit (before any barrier)
    il = p.idx + (long)(p.ebase + ze) * 2048;
  } else {
    if (p.cnt) { cntE = p.cnt[0]; if (am0 >= cntE) return; }
  }

  const long lda = p.lda, ldb = p.ldb;
  const long K = p.K;
  const long kco = (long)kc * p.kcK;

  const int sub = (lane & 7) ^ (lane >> 3);
  const int rIn = wid * 8 + (lane >> 3);

  const bf16 *aS[4], *bS[4];
  {
    const bf16* Bb = p.Bh + (long)ze * p.bBS + bn0 * ldb;
    const bf16* Ab = p.Ah + (long)ze * p.aBS + am0 * lda;
#pragma unroll
    for (int j = 0; j < 4; ++j) {
      const int row = j * 32 + rIn;
      bS[j] = Bb + (long)row * ldb + sub * 8;
      if constexpr (GATHER) {
        const int rt = (int)am0 + row;
        const long grow = il[rt < cntE ? rt : 0];
        aS[j] = p.Ah + grow * lda + sub * 8;
      } else {
        aS[j] = Ab + (long)row * lda + sub * 8;
      }
    }
  }
  char* dstA[4];
#pragma unroll
  for (int j = 0; j < 4; ++j)
    dstA[j] = (char*)(void*)lds + (j * 256 + wid * 64) * 16;

  f32x4 acc[4][4] = {};

  const int r15 = lane & 15;
  const int kcs = lane >> 4;
  const int xk  = lane & 7;

  for (long k0 = 0; k0 < K; k0 += 64) {
    const long kv = kco + k0;
    const long ka = (kv >= p.aT) ? kv - p.aS2 : kv;
    const long kb = (kv >= p.bT) ? kv - p.bS2 : kv;
    __syncthreads();
#pragma unroll
    for (int j = 0; j < 4; ++j) {
      GLOAD_LDS16(aS[j] + ka, dstA[j]);
      GLOAD_LDS16(bS[j] + kb, dstA[j] + 16384);
    }
    __syncthreads();
#pragma unroll
    for (int h = 0; h < 2; ++h) {
      const int q8 = ((kcs + 4 * h) ^ xk) << 3;
      bf16x8 a[4], b[4];
#pragma unroll
      for (int m = 0; m < 4; ++m)
        a[m] = *(const bf16x8*)(ldsA + (wr * 64 + m * 16 + r15) * 64 + q8);
#pragma unroll
      for (int n = 0; n < 4; ++n)
        b[n] = *(const bf16x8*)(ldsB + (wc * 64 + n * 16 + r15) * 64 + q8);
#pragma unroll
      for (int m = 0; m < 4; ++m)
#pragma unroll
        for (int n = 0; n < 4; ++n)
          acc[m][n] = __builtin_amdgcn_mfma_f32_16x16x32_bf16(a[m], b[n], acc[m][n], 0, 0, 0);
    }
  }

  const long N = p.N;
#pragma unroll
  for (int m = 0; m < 4; ++m) {
#pragma unroll
    for (int n = 0; n < 4; ++n) {
      const long col = bn0 + wc * 64 + n * 16 + (lane & 15);
      const float bv = (kc == 0) ? p.bias[(long)ze * p.biasBS + col] : 0.0f;
#pragma unroll
      for (int r = 0; r < 4; ++r) {
        const long row = am0 + wr * 64 + m * 16 + (lane >> 4) * 4 + r;
        float v = acc[m][n][r] + bv;
        if constexpr (EPI == EPI_GELU_SPLIT) {
          if (row < cntE) {
            float g = gelu_tanh(v);
            bf16 hh = (bf16)g;
            long o = row * (long)p.ldo + col;
            p.outH[o] = hh;
            p.outH[o + N] = (bf16)(g - (float)hh);
          }
        } else if constexpr (EPI == EPI_RESID) {
          if (row < cntE) atomicAdd(p.outF + row * N + col, v);
        } else if constexpr (EPI == EPI_GELU_BF16) {
          long o = (long)ze * p.outBS + row * N + col;
          p.outH[o] = (bf16)gelu_tanh(v);
        } else if constexpr (EPI == EPI_MOE) {
          if (row < cntE) {
            const int tok = il[row];
            const float wgt = p.rwp[(long)tok * 8 + p.ebase + ze];
            atomicAdd(p.outF + (long)tok * N + col, wgt * v);
          }
        }
      }
    }
  }
}

// ------- fast transpose: fp32 [R][C] -> bf16 [C][R] (AUG: [C][2R]=[h|l]) -----
template <bool AUG>
__global__ void transpose_cvt(const float* __restrict__ in, bf16* __restrict__ out,
                              int R, int C, long inBS, long outBS) {
  __shared__ float tile[64][65];
  const float* inp = in + (long)blockIdx.z * inBS;
  const long c0 = (long)blockIdx.x * 64;
  const long r0 = (long)blockIdx.y * 64;
  const int tx = threadIdx.x;   // 16
  const int ty = threadIdx.y;   // 16
#pragma unroll
  for (int i = 0; i < 4; ++i) {
    const int r = ty + i * 16;
    const float4 v = *(const float4*)(inp + (r0 + r) * (long)C + c0 + tx * 4);
    tile[r][tx * 4 + 0] = v.x;
    tile[r][tx * 4 + 1] = v.y;
    tile[r][tx * 4 + 2] = v.z;
    tile[r][tx * 4 + 3] = v.w;
  }
  __syncthreads();
  const long ob = (long)blockIdx.z * outBS;
  const long stride = AUG ? 2L * R : (long)R;
#pragma unroll
  for (int j = 0; j < 4; ++j) {
    const int c = j * 16 + ty;
    bf16x4 h, l;
#pragma unroll
    for (int u = 0; u < 4; ++u) {
      float v = tile[tx * 4 + u][c];
      bf16 hh = (bf16)v;
      h[u] = hh;
      if constexpr (AUG) l[u] = (bf16)(v - (float)hh);
    }
    const long o = ob + (c0 + c) * stride + r0 + tx * 4;
    *(bf16x4*)(out + o) = h;
    if constexpr (AUG) *(bf16x4*)(out + o + R) = l;
  }
}

// ------------- embedding gather -------------
__global__ void embed_kernel(const int* __restrict__ ids, const float* __restrict__ emb,
                             float* __restrict__ x) {
  const long t = blockIdx.x;
  const int id = ids[t];
  ((float4*)(x + t * 1024))[threadIdx.x] = ((const float4*)(emb + (long)id * 1024))[threadIdx.x];
}

// ------------- LayerNorm core -------------
DEV void ln_row(const float* xrow, float4& a, float& mu, float& rs,
                const int tid, const int lane, const int wid) {
  a = ((const float4*)xrow)[tid];
  float s = a.x + a.y + a.z + a.w;
  float q = a.x * a.x + a.y * a.y + a.z * a.z + a.w * a.w;
#pragma unroll
  for (int off = 32; off; off >>= 1) {
    s += __shfl_down(s, off);
    q += __shfl_down(q, off);
  }
  __shared__ float sr[4], qr[4];
  if (lane == 0) { sr[wid] = s; qr[wid] = q; }
  __syncthreads();
  s = sr[0] + sr[1] + sr[2] + sr[3];
  q = qr[0] + qr[1] + qr[2] + qr[3];
  mu = s * (1.0f / 1024.0f);
  const float var = q * (1.0f / 1024.0f) - mu * mu;
  rs = rsqrtf(var + 1e-5f);
}

// plain bf16 LN (fast pass): out [T][1024]
__global__ void ln_bf16_kernel(const float* __restrict__ x, const float* __restrict__ sc,
                               const float* __restrict__ bi, bf16* __restrict__ oh) {
  const long t = blockIdx.x;
  const int tid = threadIdx.x, lane = tid & 63, wid = tid >> 6;
  float4 a; float mu, rs;
  ln_row(x + t * 1024, a, mu, rs, tid, lane, wid);
  bf16x4 h;
#pragma unroll
  for (int j = 0; j < 4; ++j) {
    const int d = tid * 4 + j;
    h[j] = (bf16)((((const float*)&a)[j] - mu) * rs * sc[d] + bi[d]);
  }
  *(bf16x4*)(oh + t * 1024 + tid * 4) = h;
}

// compact aug LN (pass 2): in XC[b], out A1c[b] = [h|l] stride 2048
__global__ void ln_aug2c_kernel(const float* __restrict__ xc, const float* __restrict__ sc,
                                const float* __restrict__ bi, bf16* __restrict__ oa,
                                const int* __restrict__ fcnt) {
  const long b = blockIdx.x;
  if ((int)b >= *fcnt) return;
  const int tid = threadIdx.x, lane = tid & 63, wid = tid >> 6;
  float4 a; float mu, rs;
  ln_row(xc + b * 1024, a, mu, rs, tid, lane, wid);
#pragma unroll
  for (int j = 0; j < 4; ++j) {
    const int d = tid * 4 + j;
    const float g = (((const float*)&a)[j] - mu) * rs * sc[d] + bi[d];
    const bf16 h = (bf16)g;
    oa[b * 2048 + d] = h;
    oa[b * 2048 + 1024 + d] = (bf16)(g - (float)h);
  }
}

// ---- router pass 1: logits, top-2 weights, XB convert, margin flagging ----
__global__ void router_kernel(const float* __restrict__ x, const float* __restrict__ Wr,
                              const float* __restrict__ br, float* __restrict__ rwo,
                              bf16* __restrict__ xb, int* __restrict__ top2,
                              int* __restrict__ fcnt, int* __restrict__ fidx) {
  const long t = blockIdx.x;
  const int lane = threadIdx.x;  // 64
  float acc[8];
#pragma unroll
  for (int e = 0; e < 8; ++e) acc[e] = 0.0f;
  const float4* xr = (const float4*)(x + t * 1024);
#pragma unroll
  for (int j = 0; j < 4; ++j) {
    const int d4 = j * 64 + lane;
    float4 xv = xr[d4];
    bf16x4 xh;
    xh[0] = (bf16)xv.x; xh[1] = (bf16)xv.y; xh[2] = (bf16)xv.z; xh[3] = (bf16)xv.w;
    *(bf16x4*)(xb + t * 1024 + (long)d4 * 4) = xh;
#pragma unroll
    for (int u = 0; u < 4; ++u) {
      const float xs = ((const float*)&xv)[u];
      const float4* wp = (const float4*)(Wr + (long)(d4 * 4 + u) * 8);
      float4 w0 = wp[0], w1 = wp[1];
      acc[0] += xs * w0.x; acc[1] += xs * w0.y; acc[2] += xs * w0.z; acc[3] += xs * w0.w;
      acc[4] += xs * w1.x; acc[5] += xs * w1.y; acc[6] += xs * w1.z; acc[7] += xs * w1.w;
    }
  }
#pragma unroll
  for (int off = 32; off; off >>= 1)
#pragma unroll
    for (int e = 0; e < 8; ++e) acc[e] += __shfl_down(acc[e], off);
  if (lane == 0) {
    float v[8];
#pragma unroll
    for (int e = 0; e < 8; ++e) v[e] = acc[e] + br[e];
    int i0 = 0; float v0 = v[0];
    for (int e = 1; e < 8; ++e) if (v[e] > v0) { v0 = v[e]; i0 = e; }
    int i1 = -1; float v1 = -3.4e38f;
    for (int e = 0; e < 8; ++e) if (e != i0 && v[e] > v1) { v1 = v[e]; i1 = e; }
    float m3 = -3.4e38f;
    for (int e = 0; e < 8; ++e) if (e != i0 && e != i1 && v[e] > m3) m3 = v[e];
    float e1 = expf(v1 - v0);
    float den = 1.0f + e1;
    float w0 = 1.0f / den, w1 = e1 / den;
    float* o = rwo + t * 8;
#pragma unroll
    for (int e = 0; e < 8; ++e) o[e] = (e == i0) ? w0 : (e == i1 ? w1 : 0.0f);
    top2[t] = i0 | (i1 << 8);
    if (v1 - m3 < TAU) {              // ambiguous 2nd-vs-3rd: flag for exact redo
      int pp = atomicAdd(fcnt, 1);
      fidx[pp] = (int)t;
    }
  }
}

// ---- router pass 2 (flagged tokens, exact x): redo weights + top2 ----
__global__ void router2_kernel(const float* __restrict__ x, const float* __restrict__ Wr,
                               const float* __restrict__ br, float* __restrict__ rwo,
                               int* __restrict__ top2, const int* __restrict__ fcnt,
                               const int* __restrict__ fidx) {
  const int b = blockIdx.x;
  if (b >= *fcnt) return;
  const long t = fidx[b];
  const int lane = threadIdx.x;  // 64
  float acc[8];
#pragma unroll
  for (int e = 0; e < 8; ++e) acc[e] = 0.0f;
  const float4* xr = (const float4*)(x + t * 1024);
#pragma unroll
  for (int j = 0; j < 4; ++j) {
    float4 xv = xr[j * 64 + lane];
#pragma unroll
    for (int u = 0; u < 4; ++u) {
      const float xs = ((const float*)&xv)[u];
      const float4* wp = (const float4*)(Wr + (long)((j * 64 + lane) * 4 + u) * 8);
      float4 w0 = wp[0], w1 = wp[1];
      acc[0] += xs * w0.x; acc[1] += xs * w0.y; acc[2] += xs * w0.z; acc[3] += xs * w0.w;
      acc[4] += xs * w1.x; acc[5] += xs * w1.y; acc[6] += xs * w1.z; acc[7] += xs * w1.w;
    }
  }
#pragma unroll
  for (int off = 32; off; off >>= 1)
#pragma unroll
    for (int e = 0; e < 8; ++e) acc[e] += __shfl_down(acc[e], off);
  if (lane == 0) {
    float v[8];
#pragma unroll
    for (int e = 0; e < 8; ++e) v[e] = acc[e] + br[e];
    int i0 = 0; float v0 = v[0];
    for (int e = 1; e < 8; ++e) if (v[e] > v0) { v0 = v[e]; i0 = e; }
    int i1 = -1; float v1 = -3.4e38f;
    for (int e = 0; e < 8; ++e) if (e != i0 && v[e] > v1) { v1 = v[e]; i1 = e; }
    float e1 = expf(v1 - v0);
    float den = 1.0f + e1;
    float w0 = 1.0f / den, w1 = e1 / den;
    float* o = rwo + t * 8;
#pragma unroll
    for (int e = 0; e < 8; ++e) o[e] = (e == i0) ? w0 : (e == i1 ? w1 : 0.0f);
    top2[t] = i0 | (i1 << 8);
  }
}

// ------------- per-expert token list build (after router2) -------------
__global__ void build_lists(const int* __restrict__ top2, int* __restrict__ cnt,
                            int* __restrict__ idx) {
  const int t = blockIdx.x * 256 + threadIdx.x;
  const int rec = top2[t];
  const int e0 = rec & 255, e1 = (rec >> 8) & 255;
  int p0 = atomicAdd(&cnt[e0], 1);
  idx[e0 * 2048 + p0] = t;
  int p1 = atomicAdd(&cnt[e1], 1);
  idx[e1 * 2048 + p1] = t;
}

// ------------- pass-2 row gather / scatter -------------
__global__ void gather_rows(const float* __restrict__ x0, const int* __restrict__ fidx,
                            const int* __restrict__ fcnt, float* __restrict__ xc) {
  const int b = blockIdx.x;
  if (b >= *fcnt) return;
  const long t = fidx[b];
  ((float4*)(xc + (long)b * 1024))[threadIdx.x] =
      ((const float4*)(x0 + t * 1024))[threadIdx.x];
}

__global__ void scatter_rows(const float* __restrict__ xc, const int* __restrict__ fidx,
                             const int* __restrict__ fcnt, float* __restrict__ x,
                             bf16* __restrict__ xb) {
  const int b = blockIdx.x;
  if (b >= *fcnt) return;
  const long t = fidx[b];
  float4 v = ((const float4*)(xc + (long)b * 1024))[threadIdx.x];
  ((float4*)(x + t * 1024))[threadIdx.x] = v;
  bf16x4 h;
  h[0] = (bf16)v.x; h[1] = (bf16)v.y; h[2] = (bf16)v.z; h[3] = (bf16)v.w;
  *(bf16x4*)(xb + t * 1024 + (long)threadIdx.x * 4) = h;
}

// ------------- fp32 -> bf16 flat convert (YB) -------------
__global__ void cvt_bf16_kernel(const float* __restrict__ in, bf16* __restrict__ out, long n) {
  long i = ((long)blockIdx.x * blockDim.x + threadIdx.x) * 8;
  if (i >= n) return;
  float4 a = *(const float4*)(in + i);
  float4 b = *(const float4*)(in + i + 4);
  bf16x8 o;
  o[0] = (bf16)a.x; o[1] = (bf16)a.y; o[2] = (bf16)a.z; o[3] = (bf16)a.w;
  o[4] = (bf16)b.x; o[5] = (bf16)b.y; o[6] = (bf16)b.z; o[7] = (bf16)b.w;
  *(bf16x8*)(out + i) = o;
}

// ---------------- host launch ----------------
extern "C" void kernel_launch(void* const* d_in, const int* in_sizes, int n_in,
                              void* d_out, int out_size, void* d_ws, size_t ws_size,
                              hipStream_t stream) {
  (void)in_sizes; (void)n_in; (void)out_size; (void)ws_size;
  const int*   ids  = (const int*)d_in[0];
  const float* emb  = (const float*)d_in[1];
  const float* tlns = (const float*)d_in[2];
  const float* tlnb = (const float*)d_in[3];
  const float* tw1  = (const float*)d_in[4];
  const float* tb1  = (const float*)d_in[5];
  const float* tw2  = (const float*)d_in[6];
  const float* tb2  = (const float*)d_in[7];
  const float* Wr   = (const float*)d_in[8];
  const float* br   = (const float*)d_in[9];
  const float* ew1  = (const float*)d_in[10];
  const float* eb1  = (const float*)d_in[11];
  const float* ew2  = (const float*)d_in[12];
  const float* eb2  = (const float*)d_in[13];
  const float* Wl   = (const float*)d_in[14];
  const float* bl   = (const float*)d_in[15];

  float* logits = (float*)d_out;
  float* rwout  = (float*)d_out + (long)Tm * Vm;

  size_t off = 0;
  auto take = [&](size_t bytes) {
    void* pp = (char*)d_ws + off;
    off += (bytes + 255) & ~(size_t)255;
    return pp;
  };
  float* X0   = (float*)take((size_t)Tm * Dm * 4);   // pristine embeddings
  float* X    = (float*)take((size_t)Tm * Dm * 4);
  bf16*  XB   = (bf16*) take((size_t)Tm * Dm * 2);
  float* Y    = (float*)take((size_t)Tm * Dm * 4);
  bf16*  YB   = (bf16*) take((size_t)Tm * Dm * 2);
  float* XC   = (float*)take((size_t)Tm * Dm * 4);   // pass-2 compact exact x
  int*   top2 = (int*)  take((size_t)Tm * 4);
  int*   cnt  = (int*)  take(8 * 4);
  int*   fcnt = (int*)  take(256);
  int*   fidx = (int*)  take((size_t)Tm * 4);
  int*   idxl = (int*)  take((size_t)8 * Tm * 4);
  char*  S    = (char*) take(134217728);   // 128 MiB phase-shared scratch

  // temporal phase: per-layer aug weights (kept for pass 2) + shared bufs
  bf16* W1A = (bf16*)S;                    // 2 x [4096][2048]  33.6 MB
  bf16* W2A = (bf16*)(S + 33554432);       // 2 x [1024][8192]  33.6 MB
  bf16* A1  = (bf16*)(S + 67108864);       // [2048][2048]       8.4 MB (fast+c)
  bf16* HT  = (bf16*)(S + 75497472);       // [2048][8192]      33.6 MB (fast+c)
  const long W1S = 4096L * 2048, W2S = 1024L * 8192;
  // expert phase (reuses S after temporal+pass2 done)
  bf16* EW1T = (bf16*)S;                   // 4x[4096][1024] 33.6 MB
  bf16* HE   = (bf16*)(S + 33554432);      // 4x[2048][4096] 67.1 MB
  bf16* EW2T = (bf16*)(S + 100663296);     // 4x[1024][4096] 33.6 MB
  // logits phase
  bf16* WLT  = (bf16*)S;                   // [32000][1024]  65.5 MB

  embed_kernel<<<dim3(Tm), dim3(256), 0, stream>>>(ids, emb, X0);
  hipMemcpyAsync(X, X0, (size_t)Tm * Dm * 4, hipMemcpyDeviceToDevice, stream);

  // ---- FAST temporal pass: plain bf16 GEMMs (h-halves of aug weights) ----
  for (int l = 0; l < 2; ++l) {
    transpose_cvt<true><<<dim3(DFFm / 64, Dm / 64, 1), dim3(16, 16), 0, stream>>>(
        tw1 + (long)l * Dm * DFFm, W1A + l * W1S, Dm, DFFm, 0, 0);
    transpose_cvt<true><<<dim3(Dm / 64, DFFm / 64, 1), dim3(16, 16), 0, stream>>>(
        tw2 + (long)l * DFFm * Dm, W2A + l * W2S, DFFm, Dm, 0, 0);
    ln_bf16_kernel<<<dim3(Tm), dim3(256), 0, stream>>>(X, tlns + l * Dm, tlnb + l * Dm, A1);

    GemmP f1{};
    f1.Ah = A1; f1.Bh = W1A + l * W1S;
    f1.bias = tb1 + (long)l * DFFm;
    f1.outH = HT;                         // plain bf16 [2048][4096]
    f1.K = Dm; f1.N = DFFm; f1.lda = Dm; f1.ldb = 2048;
    gemm_bt<EPI_GELU_BF16, false, true>
        <<<dim3(DFFm / 128, Tm / 128, 1), dim3(256), 0, stream>>>(f1);

    GemmP f2{};
    f2.Ah = HT; f2.Bh = W2A + l * W2S;
    f2.bias = tb2 + (long)l * Dm;
    f2.outF = X;                          // X pre-holds resid; chunks atomicAdd
    f2.K = 1024; f2.N = Dm; f2.lda = DFFm; f2.ldb = 8192;
    f2.kcShift = 2; f2.kcK = 1024;
    gemm_bt<EPI_RESID, false, true>
        <<<dim3(Dm / 128, Tm / 128, 4), dim3(256), 0, stream>>>(f2);
  }

  // ---- router pass 1: logits, weights, XB, margin flags ----
  hipMemsetAsync(fcnt, 0, 4, stream);
  router_kernel<<<dim3(Tm), dim3(64), 0, stream>>>(X, Wr, br, rwout, XB, top2, fcnt, fidx);

  // ---- pass 2: exact (aug-K) recompute of flagged tokens ----
  gather_rows<<<dim3(Tm), dim3(256), 0, stream>>>(X0, fidx, fcnt, XC);
  for (int l = 0; l < 2; ++l) {
    ln_aug2c_kernel<<<dim3(Tm), dim3(256), 0, stream>>>(XC, tlns + l * Dm,
                                                        tlnb + l * Dm, A1, fcnt);
    // virtual K=3072: A [h|l|h] (phys [h|l]), B [h|h|l] (phys [h|l])
    GemmP c1{};
    c1.Ah = A1; c1.Bh = W1A + l * W1S;
    c1.bias = tb1 + (long)l * DFFm;
    c1.outH = HT;                         // compact [F][h|l], ldo = 2*DFF
    c1.K = 3072; c1.N = DFFm; c1.lda = 2048; c1.ldb = 2048; c1.ldo = 2 * DFFm;
    c1.aT = 2048; c1.aS2 = 2048; c1.bT = 1024; c1.bS2 = 1024;
    c1.cnt = fcnt;
    gemm_bt<EPI_GELU_SPLIT, false, true>
        <<<dim3(DFFm / 128, Tm / 128, 1), dim3(256), 0, stream>>>(c1);

    // virtual K=12288 split-K 8 -> XC += (XC pre-holds exact x_prev)
    GemmP c2{};
    c2.Ah = HT; c2.Bh = W2A + l * W2S;
    c2.bias = tb2 + (long)l * Dm;
    c2.outF = XC;
    c2.K = 1536; c2.N = Dm; c2.lda = 8192; c2.ldb = 8192;
    c2.kcShift = 3; c2.kcK = 1536;
    c2.aT = 8192; c2.aS2 = 8192; c2.bT = 4096; c2.bS2 = 4096;
    c2.cnt = fcnt;
    gemm_bt<EPI_RESID, false, true>
        <<<dim3(Dm / 128, Tm / 128, 8), dim3(256), 0, stream>>>(c2);
  }
  scatter_rows<<<dim3(Tm), dim3(256), 0, stream>>>(XC, fidx, fcnt, X, XB);
  router2_kernel<<<dim3(Tm), dim3(64), 0, stream>>>(X, Wr, br, rwout, top2, fcnt, fidx);

  // ---- expert token lists (after routing finalized) ----
  hipMemsetAsync(cnt, 0, 8 * 4, stream);
  build_lists<<<dim3(Tm / 256), dim3(256), 0, stream>>>(top2, cnt, idxl);
  hipMemsetAsync(Y, 0, (size_t)Tm * Dm * 4, stream);

  // ---- sparse top-2 expert stack, 2 quads of 4 experts (bf16) ----
  for (int q = 0; q < 2; ++q) {
    transpose_cvt<false><<<dim3(DFFm / 64, Dm / 64, 4), dim3(16, 16), 0, stream>>>(
        ew1 + (long)q * 4 * Dm * DFFm, EW1T, Dm, DFFm, (long)Dm * DFFm, (long)DFFm * Dm);
    transpose_cvt<false><<<dim3(Dm / 64, DFFm / 64, 4), dim3(16, 16), 0, stream>>>(
        ew2 + (long)q * 4 * DFFm * Dm, EW2T, DFFm, Dm, (long)DFFm * Dm, (long)Dm * DFFm);

    GemmP pe1{};
    pe1.Ah = XB; pe1.Bh = EW1T;
    pe1.bias = eb1 + (long)q * 4 * DFFm; pe1.biasBS = DFFm;
    pe1.outH = HE; pe1.outBS = (long)Tm * DFFm;
    pe1.aBS = 0; pe1.bBS = (long)DFFm * Dm;
    pe1.cnt = cnt; pe1.idx = idxl; pe1.ebase = q * 4;
    pe1.K = Dm; pe1.N = DFFm; pe1.lda = Dm; pe1.ldb = Dm;
    gemm_bt<EPI_GELU_BF16, true, true>
        <<<dim3(DFFm / 128, Tm / 128, 4), dim3(256), 0, stream>>>(pe1);

    GemmP pe2{};
    pe2.Ah = HE; pe2.aBS = (long)Tm * DFFm;
    pe2.Bh = EW2T; pe2.bBS = (long)Dm * DFFm;
    pe2.bias = eb2 + (long)q * 4 * Dm; pe2.biasBS = Dm;
    pe2.rwp = rwout; pe2.cnt = cnt; pe2.idx = idxl; pe2.ebase = q * 4;
    pe2.outF = Y;
    pe2.K = 1024; pe2.N = Dm; pe2.lda = DFFm; pe2.ldb = DFFm;
    pe2.kcShift = 2; pe2.kcK = 1024;
    gemm_bt<EPI_MOE, false, true>
        <<<dim3(Dm / 128, Tm / 128, 16), dim3(256), 0, stream>>>(pe2);
  }

  // ---- final logits GEMM: 256^2 8-phase pipeline (R7/R8) ----
  cvt_bf16_kernel<<<dim3(Tm * Dm / (256 * 8)), dim3(256), 0, stream>>>(Y, YB, (long)Tm * Dm);
  transpose_cvt<false><<<dim3(Vm / 64, Dm / 64, 1), dim3(16, 16), 0, stream>>>(
      Wl, WLT, Dm, Vm, 0, 0);
  gemm256_8p<true><<<dim3(Vm / 256, Tm / 256, 1), dim3(512), 0, stream>>>(
      YB, WLT, bl, logits, Dm, Vm);
}

// Round 12
// 978.487 us; speedup vs baseline: 1.1346x; 1.1346x over previous
//
#include <hip/hip_runtime.h>
#include <stdint.h>

typedef __bf16 bf16;
typedef __bf16 bf16x8 __attribute__((ext_vector_type(8)));
typedef __bf16 bf16x4 __attribute__((ext_vector_type(4)));
typedef float f32x4 __attribute__((ext_vector_type(4)));

#define DEV __device__ __forceinline__

static constexpr int Dm   = 1024;
static constexpr int DFFm = 4096;
static constexpr int Tm   = 2048;   // B*S tokens
static constexpr int Vm   = 32000;

// ---------------- helpers ----------------
#define GLOAD_LDS16(g, l)                                                      \
  __builtin_amdgcn_global_load_lds(                                            \
      (const __attribute__((address_space(1))) unsigned int*)(g),              \
      (__attribute__((address_space(3))) unsigned int*)(l), 16, 0, 0)

DEV float gelu_tanh(float v) {  // matches jax.nn.gelu (approximate=True)
  float u = 0.7978845608028654f * (v + 0.044715f * v * v * v);
  float e = __expf(2.0f * u);
  float t = 1.0f - 2.0f / (e + 1.0f);
  return 0.5f * v * (1.0f + t);
}

// =======================================================================
// 256^2 / 8-wave / 8-phase GEMM (logits) — R7/R8 verified.
// =======================================================================
template <bool SWZ>
__launch_bounds__(512, 2)
__global__ void gemm256_8p(const bf16* __restrict__ A, const bf16* __restrict__ B,
                           const float* __restrict__ bias, float* __restrict__ out,
                           int Kc, int Nc) {
  __shared__ bf16 lds[65536];   // 128 KiB: 2 buf x (A[256][64] | B[256][64])
  const int tid  = threadIdx.x;
  const int lane = tid & 63;
  const int wid  = tid >> 6;
  const int wr   = wid >> 2;
  const int wc   = wid & 3;

  int bx = blockIdx.x, by = blockIdx.y;
  if constexpr (SWZ) {
    const int gx = gridDim.x, gy = gridDim.y;
    const int nwg = gx * gy;
    const int lin = by * gx + bx;
    const int q = nwg >> 3, r = nwg & 7;
    const int xcd = lin & 7, loc = lin >> 3;
    const int nid = (xcd < r ? xcd * (q + 1) : r * (q + 1) + (xcd - r) * q) + loc;
    bx = nid / gy; by = nid % gy;
  }
  const long am0 = (long)by * 256;
  const long bn0 = (long)bx * 256;
  const long K = Kc;
  const int NT = Kc >> 6;

  const int sub = (lane & 7) ^ (lane >> 3);
  const int rw  = wid * 8 + (lane >> 3);
  const bf16 *aS[4], *bS[4];
#pragma unroll
  for (int j = 0; j < 4; ++j) {
    aS[j] = A + (am0 + j * 64 + rw) * K + sub * 8;
    bS[j] = B + (bn0 + j * 64 + rw) * K + sub * 8;
  }
  char* ldsc = (char*)(void*)lds;

#define STG_A(kt, j)                                                           \
  GLOAD_LDS16(aS[j] + (long)(kt) * 64,                                         \
              ldsc + ((kt) & 1) * 65536 + ((j) * 64 + wid * 8) * 128)
#define STG_B(kt, j)                                                           \
  GLOAD_LDS16(bS[j] + (long)(kt) * 64,                                         \
              ldsc + ((kt) & 1) * 65536 + 32768 + ((j) * 64 + wid * 8) * 128)

  STG_B(0, 0); STG_B(0, 1); STG_B(0, 2); STG_B(0, 3);
  STG_A(0, 0); STG_A(0, 2); STG_A(0, 1); STG_A(0, 3);
  if (NT > 1) {
    STG_B(1, 0); STG_B(1, 1); STG_B(1, 2); STG_B(1, 3);
    STG_A(1, 0); STG_A(1, 2);
    asm volatile("s_waitcnt vmcnt(6)" ::: "memory");
  } else {
    asm volatile("s_waitcnt vmcnt(0)" ::: "memory");
  }
  __builtin_amdgcn_s_barrier();

  f32x4 acc[8][4] = {};
  const int r15 = lane & 15;
  const int kcs = lane >> 4;
  const int x7  = lane & 7;
  const int q80 = (kcs ^ x7) << 3;
  const int q81 = ((kcs + 4) ^ x7) << 3;

  for (int t = 0; t < NT; ++t) {
    const bf16* LAb = lds + (t & 1) * 32768 + wr * 128 * 64;
    const bf16* LBb = lds + (t & 1) * 32768 + 16384 + wc * 64 * 64;
    bf16x8 b0[4], b1[4];

    {
      bf16x8 a0, a1, a2, a3;
#pragma unroll
      for (int n = 0; n < 4; ++n) {
        b0[n] = *(const bf16x8*)(LBb + (n * 16 + r15) * 64 + q80);
        b1[n] = *(const bf16x8*)(LBb + (n * 16 + r15) * 64 + q81);
      }
      a0 = *(const bf16x8*)(LAb + (0 * 16 + r15) * 64 + q80);
      a1 = *(const bf16x8*)(LAb + (0 * 16 + r15) * 64 + q81);
      a2 = *(const bf16x8*)(LAb + (1 * 16 + r15) * 64 + q80);
      a3 = *(const bf16x8*)(LAb + (1 * 16 + r15) * 64 + q81);
      if (t + 1 < NT) { STG_A(t + 1, 1); STG_A(t + 1, 3); }
      __builtin_amdgcn_s_barrier();
      asm volatile("s_waitcnt lgkmcnt(0)" ::: "memory");
      __builtin_amdgcn_s_setprio(1);
#pragma unroll
      for (int n = 0; n < 4; ++n) {
        acc[0][n] = __builtin_amdgcn_mfma_f32_16x16x32_bf16(a0, b0[n], acc[0][n], 0, 0, 0);
        acc[0][n] = __builtin_amdgcn_mfma_f32_16x16x32_bf16(a1, b1[n], acc[0][n], 0, 0, 0);
        acc[1][n] = __builtin_amdgcn_mfma_f32_16x16x32_bf16(a2, b0[n], acc[1][n], 0, 0, 0);
        acc[1][n] = __builtin_amdgcn_mfma_f32_16x16x32_bf16(a3, b1[n], acc[1][n], 0, 0, 0);
      }
      __builtin_amdgcn_s_setprio(0);
      __builtin_amdgcn_s_barrier();
    }
    {
      bf16x8 a0, a1, a2, a3;
      a0 = *(const bf16x8*)(LAb + (2 * 16 + r15) * 64 + q80);
      a1 = *(const bf16x8*)(LAb + (2 * 16 + r15) * 64 + q81);
      a2 = *(const bf16x8*)(LAb + (3 * 16 + r15) * 64 + q80);
      a3 = *(const bf16x8*)(LAb + (3 * 16 + r15) * 64 + q81);
      if (t + 2 < NT) { STG_B(t + 2, 0); STG_B(t + 2, 1); }
      __builtin_amdgcn_s_barrier();
      asm volatile("s_waitcnt lgkmcnt(0)" ::: "memory");
      __builtin_amdgcn_s_setprio(1);
#pragma unroll
      for (int n = 0; n < 4; ++n) {
        acc[2][n] = __builtin_amdgcn_mfma_f32_16x16x32_bf16(a0, b0[n], acc[2][n], 0, 0, 0);
        acc[2][n] = __builtin_amdgcn_mfma_f32_16x16x32_bf16(a1, b1[n], acc[2][n], 0, 0, 0);
        acc[3][n] = __builtin_amdgcn_mfma_f32_16x16x32_bf16(a2, b0[n], acc[3][n], 0, 0, 0);
        acc[3][n] = __builtin_amdgcn_mfma_f32_16x16x32_bf16(a3, b1[n], acc[3][n], 0, 0, 0);
      }
      __builtin_amdgcn_s_setprio(0);
      __builtin_amdgcn_s_barrier();
    }
    {
      bf16x8 a0, a1, a2, a3;
      a0 = *(const bf16x8*)(LAb + (4 * 16 + r15) * 64 + q80);
      a1 = *(const bf16x8*)(LAb + (4 * 16 + r15) * 64 + q81);
      a2 = *(const bf16x8*)(LAb + (5 * 16 + r15) * 64 + q80);
      a3 = *(const bf16x8*)(LAb + (5 * 16 + r15) * 64 + q81);
      if (t + 2 < NT) { STG_B(t + 2, 2); STG_B(t + 2, 3); }
      __builtin_amdgcn_s_barrier();
      asm volatile("s_waitcnt lgkmcnt(0)" ::: "memory");
      __builtin_amdgcn_s_setprio(1);
#pragma unroll
      for (int n = 0; n < 4; ++n) {
        acc[4][n] = __builtin_amdgcn_mfma_f32_16x16x32_bf16(a0, b0[n], acc[4][n], 0, 0, 0);
        acc[4][n] = __builtin_amdgcn_mfma_f32_16x16x32_bf16(a1, b1[n], acc[4][n], 0, 0, 0);
        acc[5][n] = __builtin_amdgcn_mfma_f32_16x16x32_bf16(a2, b0[n], acc[5][n], 0, 0, 0);
        acc[5][n] = __builtin_amdgcn_mfma_f32_16x16x32_bf16(a3, b1[n], acc[5][n], 0, 0, 0);
      }
      __builtin_amdgcn_s_setprio(0);
      __builtin_amdgcn_s_barrier();
    }
    {
      bf16x8 a0, a1, a2, a3;
      a0 = *(const bf16x8*)(LAb + (6 * 16 + r15) * 64 + q80);
      a1 = *(const bf16x8*)(LAb + (6 * 16 + r15) * 64 + q81);
      a2 = *(const bf16x8*)(LAb + (7 * 16 + r15) * 64 + q80);
      a3 = *(const bf16x8*)(LAb + (7 * 16 + r15) * 64 + q81);
      if (t + 2 < NT) {
        STG_A(t + 2, 0); STG_A(t + 2, 2);
        asm volatile("s_waitcnt vmcnt(6)" ::: "memory");
      } else if (t + 1 < NT) {
        asm volatile("s_waitcnt vmcnt(0)" ::: "memory");
      }
      __builtin_amdgcn_s_barrier();
      asm volatile("s_waitcnt lgkmcnt(0)" ::: "memory");
      __builtin_amdgcn_s_setprio(1);
#pragma unroll
      for (int n = 0; n < 4; ++n) {
        acc[6][n] = __builtin_amdgcn_mfma_f32_16x16x32_bf16(a0, b0[n], acc[6][n], 0, 0, 0);
        acc[6][n] = __builtin_amdgcn_mfma_f32_16x16x32_bf16(a1, b1[n], acc[6][n], 0, 0, 0);
        acc[7][n] = __builtin_amdgcn_mfma_f32_16x16x32_bf16(a2, b0[n], acc[7][n], 0, 0, 0);
        acc[7][n] = __builtin_amdgcn_mfma_f32_16x16x32_bf16(a3, b1[n], acc[7][n], 0, 0, 0);
      }
      __builtin_amdgcn_s_setprio(0);
      __builtin_amdgcn_s_barrier();
    }
  }
#undef STG_A
#undef STG_B

  const long N = Nc;
#pragma unroll
  for (int m = 0; m < 8; ++m) {
#pragma unroll
    for (int n = 0; n < 4; ++n) {
      const long col = bn0 + wc * 64 + n * 16 + r15;
      const float bv = bias[col];
#pragma unroll
      for (int r = 0; r < 4; ++r) {
        const long row = am0 + wr * 128 + m * 16 + (lane >> 4) * 4 + r;
        out[row * N + col] = acc[m][n][r] + bv;
      }
    }
  }
}

// ---------------- 128^2 GEMM with augmented-K wrap remap (R8 verified) -----
enum { EPI_GELU_SPLIT = 0, EPI_RESID = 1, EPI_GELU_BF16 = 2, EPI_MOE = 3 };

struct GemmP {
  const bf16* Ah;
  const bf16* Bh;
  const float* bias;
  const float* rwp;     // routing weights [T][8]
  const int* cnt;       // per-expert token counts [8]
  const int* idx;       // per-expert token lists [8][2048]
  float* outF;
  bf16* outH;
  int K; int N;
  int lda; int ldb; int ldo;
  long aBS, bBS, outBS;        // per-ze strides
  int biasBS;
  int ebase;                   // global expert base for ze=0
  int kcShift; int kcK;        // split-K: z = (ze << kcShift) | kc
  int aT, aS2, bT, bS2;        // k-wrap remap (0 => identity)
};

template <int EPI, bool GATHER, bool SWZ>
__launch_bounds__(256, 2)
__global__ void gemm_bt(GemmP p) {
  __shared__ bf16 lds[16384];          // A[128][64] | B[128][64], 32 KiB
  bf16* ldsA = lds;
  bf16* ldsB = lds + 8192;

  const int tid  = threadIdx.x;
  const int lane = tid & 63;
  const int wid  = tid >> 6;
  const int wr   = wid >> 1;
  const int wc   = wid & 1;
  const int z    = blockIdx.z;
  const int kc   = z & ((1 << p.kcShift) - 1);
  const int ze   = z >> p.kcShift;

  int bx = blockIdx.x, by = blockIdx.y;
  if constexpr (SWZ) {
    const int gx = gridDim.x, gy = gridDim.y;
    const int nwg = gx * gy;
    const int lin = by * gx + bx;
    const int q = nwg >> 3, r = nwg & 7;
    const int xcd = lin & 7, loc = lin >> 3;
    const int nid = (xcd < r ? xcd * (q + 1) : r * (q + 1) + (xcd - r) * q) + loc;
    bx = nid / gy; by = nid % gy;
  }

  const long am0 = (long)by * 128;
  const long bn0 = (long)bx * 128;

  int cntE = 0;
  const int* il = nullptr;
  if constexpr (GATHER || EPI == EPI_MOE) {
    cntE = p.cnt[p.ebase + ze];
    if (am0 >= cntE) return;  // wave-uniform early exit (before any barrier)
    il = p.idx + (long)(p.ebase + ze) * 2048;
  }

  const long lda = p.lda, ldb = p.ldb;
  const long K = p.K;
  const long kco = (long)kc * p.kcK;

  const int sub = (lane & 7) ^ (lane >> 3);
  const int rIn = wid * 8 + (lane >> 3);

  const bf16 *aS[4], *bS[4];
  {
    const bf16* Bb = p.Bh + (long)ze * p.bBS + bn0 * ldb;
    const bf16* Ab = p.Ah + (long)ze * p.aBS + am0 * lda;
#pragma unroll
    for (int j = 0; j < 4; ++j) {
      const int row = j * 32 + rIn;
      bS[j] = Bb + (long)row * ldb + sub * 8;
      if constexpr (GATHER) {
        const int rt = (int)am0 + row;
        const long grow = il[rt < cntE ? rt : 0];
        aS[j] = p.Ah + grow * lda + sub * 8;
      } else {
        aS[j] = Ab + (long)row * lda + sub * 8;
      }
    }
  }
  char* dstA[4];
#pragma unroll
  for (int j = 0; j < 4; ++j)
    dstA[j] = (char*)(void*)lds + (j * 256 + wid * 64) * 16;

  f32x4 acc[4][4] = {};

  const int r15 = lane & 15;
  const int kcs = lane >> 4;
  const int xk  = lane & 7;

  for (long k0 = 0; k0 < K; k0 += 64) {
    const long kv = kco + k0;
    const long ka = (kv >= p.aT) ? kv - p.aS2 : kv;
    const long kb = (kv >= p.bT) ? kv - p.bS2 : kv;
    __syncthreads();
#pragma unroll
    for (int j = 0; j < 4; ++j) {
      GLOAD_LDS16(aS[j] + ka, dstA[j]);
      GLOAD_LDS16(bS[j] + kb, dstA[j] + 16384);
    }
    __syncthreads();
#pragma unroll
    for (int h = 0; h < 2; ++h) {
      const int q8 = ((kcs + 4 * h) ^ xk) << 3;
      bf16x8 a[4], b[4];
#pragma unroll
      for (int m = 0; m < 4; ++m)
        a[m] = *(const bf16x8*)(ldsA + (wr * 64 + m * 16 + r15) * 64 + q8);
#pragma unroll
      for (int n = 0; n < 4; ++n)
        b[n] = *(const bf16x8*)(ldsB + (wc * 64 + n * 16 + r15) * 64 + q8);
#pragma unroll
      for (int m = 0; m < 4; ++m)
#pragma unroll
        for (int n = 0; n < 4; ++n)
          acc[m][n] = __builtin_amdgcn_mfma_f32_16x16x32_bf16(a[m], b[n], acc[m][n], 0, 0, 0);
    }
  }

  const long N = p.N;
#pragma unroll
  for (int m = 0; m < 4; ++m) {
#pragma unroll
    for (int n = 0; n < 4; ++n) {
      const long col = bn0 + wc * 64 + n * 16 + (lane & 15);
      const float bv = (kc == 0) ? p.bias[(long)ze * p.biasBS + col] : 0.0f;
#pragma unroll
      for (int r = 0; r < 4; ++r) {
        const long row = am0 + wr * 64 + m * 16 + (lane >> 4) * 4 + r;
        float v = acc[m][n][r] + bv;
        if constexpr (EPI == EPI_GELU_SPLIT) {
          // write [h|l] row (phys stride ldo = 2N)
          float g = gelu_tanh(v);
          bf16 hh = (bf16)g;
          long o = row * (long)p.ldo + col;
          p.outH[o] = hh;
          p.outH[o + N] = (bf16)(g - (float)hh);
        } else if constexpr (EPI == EPI_RESID) {
          atomicAdd(p.outF + row * N + col, v);
        } else if constexpr (EPI == EPI_GELU_BF16) {
          long o = (long)ze * p.outBS + row * N + col;
          p.outH[o] = (bf16)gelu_tanh(v);
        } else if constexpr (EPI == EPI_MOE) {
          if (row < cntE) {
            const int tok = il[row];
            const float wgt = p.rwp[(long)tok * 8 + p.ebase + ze];
            atomicAdd(p.outF + (long)tok * N + col, wgt * v);
          }
        }
      }
    }
  }
}

// ------- fast transpose: fp32 [R][C] -> bf16 [C][R] (AUG: [C][2R]=[h|l]) -----
template <bool AUG>
__global__ void transpose_cvt(const float* __restrict__ in, bf16* __restrict__ out,
                              int R, int C, long inBS, long outBS) {
  __shared__ float tile[64][65];
  const float* inp = in + (long)blockIdx.z * inBS;
  const long c0 = (long)blockIdx.x * 64;
  const long r0 = (long)blockIdx.y * 64;
  const int tx = threadIdx.x;   // 16
  const int ty = threadIdx.y;   // 16
#pragma unroll
  for (int i = 0; i < 4; ++i) {
    const int r = ty + i * 16;
    const float4 v = *(const float4*)(inp + (r0 + r) * (long)C + c0 + tx * 4);
    tile[r][tx * 4 + 0] = v.x;
    tile[r][tx * 4 + 1] = v.y;
    tile[r][tx * 4 + 2] = v.z;
    tile[r][tx * 4 + 3] = v.w;
  }
  __syncthreads();
  const long ob = (long)blockIdx.z * outBS;
  const long stride = AUG ? 2L * R : (long)R;
#pragma unroll
  for (int j = 0; j < 4; ++j) {
    const int c = j * 16 + ty;
    bf16x4 h, l;
#pragma unroll
    for (int u = 0; u < 4; ++u) {
      float v = tile[tx * 4 + u][c];
      bf16 hh = (bf16)v;
      h[u] = hh;
      if constexpr (AUG) l[u] = (bf16)(v - (float)hh);
    }
    const long o = ob + (c0 + c) * stride + r0 + tx * 4;
    *(bf16x4*)(out + o) = h;
    if constexpr (AUG) *(bf16x4*)(out + o + R) = l;
  }
}

// ------------- embedding gather -------------
__global__ void embed_kernel(const int* __restrict__ ids, const float* __restrict__ emb,
                             float* __restrict__ x) {
  const long t = blockIdx.x;
  const int id = ids[t];
  ((float4*)(x + t * 1024))[threadIdx.x] = ((const float4*)(emb + (long)id * 1024))[threadIdx.x];
}

// ------------- LayerNorm -> bf16 [h|l] row (stride 2048) -------------
__global__ void ln_aug2_kernel(const float* __restrict__ x, const float* __restrict__ sc,
                               const float* __restrict__ bi, bf16* __restrict__ oa) {
  const long t = blockIdx.x;
  const int tid = threadIdx.x;  // 256
  const int lane = tid & 63, wid = tid >> 6;
  float4 a = ((const float4*)(x + t * 1024))[tid];
  float s = a.x + a.y + a.z + a.w;
  float q = a.x * a.x + a.y * a.y + a.z * a.z + a.w * a.w;
#pragma unroll
  for (int off = 32; off; off >>= 1) {
    s += __shfl_down(s, off);
    q += __shfl_down(q, off);
  }
  __shared__ float sr[4], qr[4];
  if (lane == 0) { sr[wid] = s; qr[wid] = q; }
  __syncthreads();
  s = sr[0] + sr[1] + sr[2] + sr[3];
  q = qr[0] + qr[1] + qr[2] + qr[3];
  const float mu = s * (1.0f / 1024.0f);
  const float var = q * (1.0f / 1024.0f) - mu * mu;
  const float rs = rsqrtf(var + 1e-5f);
#pragma unroll
  for (int j = 0; j < 4; ++j) {
    const int d = tid * 4 + j;
    const float g = (((const float*)&a)[j] - mu) * rs * sc[d] + bi[d];
    const bf16 h = (bf16)g;
    oa[t * 2048 + d] = h;
    oa[t * 2048 + 1024 + d] = (bf16)(g - (float)h);
  }
}

// ---- router fused: logits, top-2 softmax scatter, expert lists, X->bf16 ----
__global__ void router_kernel(const float* __restrict__ x, const float* __restrict__ Wr,
                              const float* __restrict__ br, float* __restrict__ rwo,
                              bf16* __restrict__ xb, int* __restrict__ cnt,
                              int* __restrict__ idx) {
  const long t = blockIdx.x;
  const int lane = threadIdx.x;  // 64
  float acc[8];
#pragma unroll
  for (int e = 0; e < 8; ++e) acc[e] = 0.0f;
  const float4* xr = (const float4*)(x + t * 1024);
#pragma unroll
  for (int j = 0; j < 4; ++j) {
    const int d4 = j * 64 + lane;
    float4 xv = xr[d4];
    bf16x4 xh;
    xh[0] = (bf16)xv.x; xh[1] = (bf16)xv.y; xh[2] = (bf16)xv.z; xh[3] = (bf16)xv.w;
    *(bf16x4*)(xb + t * 1024 + (long)d4 * 4) = xh;
#pragma unroll
    for (int u = 0; u < 4; ++u) {
      const float xs = ((const float*)&xv)[u];
      const float4* wp = (const float4*)(Wr + (long)(d4 * 4 + u) * 8);
      float4 w0 = wp[0], w1 = wp[1];
      acc[0] += xs * w0.x; acc[1] += xs * w0.y; acc[2] += xs * w0.z; acc[3] += xs * w0.w;
      acc[4] += xs * w1.x; acc[5] += xs * w1.y; acc[6] += xs * w1.z; acc[7] += xs * w1.w;
    }
  }
#pragma unroll
  for (int off = 32; off; off >>= 1)
#pragma unroll
    for (int e = 0; e < 8; ++e) acc[e] += __shfl_down(acc[e], off);
  if (lane == 0) {
    float v[8];
#pragma unroll
    for (int e = 0; e < 8; ++e) v[e] = acc[e] + br[e];
    int i0 = 0; float v0 = v[0];
    for (int e = 1; e < 8; ++e) if (v[e] > v0) { v0 = v[e]; i0 = e; }
    int i1 = -1; float v1 = -3.4e38f;
    for (int e = 0; e < 8; ++e) if (e != i0 && v[e] > v1) { v1 = v[e]; i1 = e; }
    float e1 = expf(v1 - v0);
    float den = 1.0f + e1;
    float w0 = 1.0f / den, w1 = e1 / den;
    float* o = rwo + t * 8;
#pragma unroll
    for (int e = 0; e < 8; ++e) o[e] = (e == i0) ? w0 : (e == i1 ? w1 : 0.0f);
    int p0 = atomicAdd(&cnt[i0], 1);
    idx[i0 * 2048 + p0] = (int)t;
    int p1 = atomicAdd(&cnt[i1], 1);
    idx[i1 * 2048 + p1] = (int)t;
  }
}

// ------------- fp32 -> bf16 flat convert (YB) -------------
__global__ void cvt_bf16_kernel(const float* __restrict__ in, bf16* __restrict__ out, long n) {
  long i = ((long)blockIdx.x * blockDim.x + threadIdx.x) * 8;
  if (i >= n) return;
  float4 a = *(const float4*)(in + i);
  float4 b = *(const float4*)(in + i + 4);
  bf16x8 o;
  o[0] = (bf16)a.x; o[1] = (bf16)a.y; o[2] = (bf16)a.z; o[3] = (bf16)a.w;
  o[4] = (bf16)b.x; o[5] = (bf16)b.y; o[6] = (bf16)b.z; o[7] = (bf16)b.w;
  *(bf16x8*)(out + i) = o;
}

// ---------------- host launch ----------------
extern "C" void kernel_launch(void* const* d_in, const int* in_sizes, int n_in,
                              void* d_out, int out_size, void* d_ws, size_t ws_size,
                              hipStream_t stream) {
  (void)in_sizes; (void)n_in; (void)out_size; (void)ws_size;
  const int*   ids  = (const int*)d_in[0];
  const float* emb  = (const float*)d_in[1];
  const float* tlns = (const float*)d_in[2];
  const float* tlnb = (const float*)d_in[3];
  const float* tw1  = (const float*)d_in[4];
  const float* tb1  = (const float*)d_in[5];
  const float* tw2  = (const float*)d_in[6];
  const float* tb2  = (const float*)d_in[7];
  const float* Wr   = (const float*)d_in[8];
  const float* br   = (const float*)d_in[9];
  const float* ew1  = (const float*)d_in[10];
  const float* eb1  = (const float*)d_in[11];
  const float* ew2  = (const float*)d_in[12];
  const float* eb2  = (const float*)d_in[13];
  const float* Wl   = (const float*)d_in[14];
  const float* bl   = (const float*)d_in[15];

  float* logits = (float*)d_out;
  float* rwout  = (float*)d_out + (long)Tm * Vm;

  size_t off = 0;
  auto take = [&](size_t bytes) {
    void* pp = (char*)d_ws + off;
    off += (bytes + 255) & ~(size_t)255;
    return pp;
  };
  float* X    = (float*)take((size_t)Tm * Dm * 4);
  bf16*  XB   = (bf16*) take((size_t)Tm * Dm * 2);
  float* Y    = (float*)take((size_t)Tm * Dm * 4);
  bf16*  YB   = (bf16*) take((size_t)Tm * Dm * 2);
  int*   cnt  = (int*)  take(8 * 4);
  int*   idxl = (int*)  take((size_t)8 * Tm * 4);
  char*  S    = (char*) take(134217728);   // 128 MiB phase-shared scratch

  // temporal phase ([h|l] compressed augmented layout + k-wrap remap)
  bf16* A1  = (bf16*)S;                    // [2048][2048]   8.4 MB
  bf16* W1A = (bf16*)(S + 8388608);        // [4096][2048]  16.8 MB
  bf16* W2A = (bf16*)(S + 25165824);       // [1024][8192]  16.8 MB
  bf16* HTA = (bf16*)(S + 41943040);       // [2048][8192]  33.6 MB (end 75.5)
  // expert phase
  bf16* EW1T = (bf16*)S;                   // 4x[4096][1024] 33.6 MB
  bf16* HE   = (bf16*)(S + 33554432);      // 4x[2048][4096] 67.1 MB
  bf16* EW2T = (bf16*)(S + 100663296);     // 4x[1024][4096] 33.6 MB
  // logits phase
  bf16* WLT  = (bf16*)S;                   // [32000][1024]  65.5 MB

  embed_kernel<<<dim3(Tm), dim3(256), 0, stream>>>(ids, emb, X);

  // ---- temporal residual MLP blocks: augmented-K GEMMs ([h|l] storage) ----
  for (int l = 0; l < 2; ++l) {
    transpose_cvt<true><<<dim3(DFFm / 64, Dm / 64, 1), dim3(16, 16), 0, stream>>>(
        tw1 + (long)l * Dm * DFFm, W1A, Dm, DFFm, 0, 0);
    transpose_cvt<true><<<dim3(Dm / 64, DFFm / 64, 1), dim3(16, 16), 0, stream>>>(
        tw2 + (long)l * DFFm * Dm, W2A, DFFm, Dm, 0, 0);
    ln_aug2_kernel<<<dim3(Tm), dim3(256), 0, stream>>>(X, tlns + l * Dm, tlnb + l * Dm, A1);

    // virtual K=3072: A [h|l|h] (phys [h|l], aT=2048,aS2=2048),
    //                 B [h|h|l] (phys [h|l], bT=1024,bS2=1024)
    GemmP p1{};
    p1.Ah = A1; p1.Bh = W1A;
    p1.bias = tb1 + (long)l * DFFm;
    p1.outH = HTA;
    p1.K = 3072; p1.N = DFFm; p1.lda = 2048; p1.ldb = 2048; p1.ldo = 2 * DFFm;
    p1.aT = 2048; p1.aS2 = 2048; p1.bT = 1024; p1.bS2 = 1024;
    gemm_bt<EPI_GELU_SPLIT, false, true>
        <<<dim3(DFFm / 128, Tm / 128, 1), dim3(256), 0, stream>>>(p1);

    // virtual K=12288 split-K 8: A (phys 8192, aT=8192,aS2=8192),
    //                            B (phys 8192, bT=4096,bS2=4096)
    GemmP p2{};
    p2.Ah = HTA; p2.Bh = W2A;
    p2.bias = tb2 + (long)l * Dm;
    p2.outF = X;                         // X pre-holds residual; chunks atomicAdd
    p2.K = 1536; p2.N = Dm; p2.lda = 8192; p2.ldb = 8192;
    p2.kcShift = 3; p2.kcK = 1536;
    p2.aT = 8192; p2.aS2 = 8192; p2.bT = 4096; p2.bS2 = 4096;
    gemm_bt<EPI_RESID, false, true>
        <<<dim3(Dm / 128, Tm / 128, 8), dim3(256), 0, stream>>>(p2);
  }

  // ---- router (fp32) fused with token lists + XB convert ----
  hipMemsetAsync(cnt, 0, 8 * 4, stream);
  router_kernel<<<dim3(Tm), dim3(64), 0, stream>>>(X, Wr, br, rwout, XB, cnt, idxl);
  hipMemsetAsync(Y, 0, (size_t)Tm * Dm * 4, stream);

  // ---- sparse top-2 expert stack, 2 quads of 4 experts (bf16, 128^2) ----
  for (int q = 0; q < 2; ++q) {
    transpose_cvt<false><<<dim3(DFFm / 64, Dm / 64, 4), dim3(16, 16), 0, stream>>>(
        ew1 + (long)q * 4 * Dm * DFFm, EW1T, Dm, DFFm, (long)Dm * DFFm, (long)DFFm * Dm);
    transpose_cvt<false><<<dim3(Dm / 64, DFFm / 64, 4), dim3(16, 16), 0, stream>>>(
        ew2 + (long)q * 4 * DFFm * Dm, EW2T, DFFm, Dm, (long)DFFm * Dm, (long)Dm * DFFm);

    GemmP pe1{};
    pe1.Ah = XB; pe1.Bh = EW1T;
    pe1.bias = eb1 + (long)q * 4 * DFFm; pe1.biasBS = DFFm;
    pe1.outH = HE; pe1.outBS = (long)Tm * DFFm;
    pe1.aBS = 0; pe1.bBS = (long)DFFm * Dm;
    pe1.cnt = cnt; pe1.idx = idxl; pe1.ebase = q * 4;
    pe1.K = Dm; pe1.N = DFFm; pe1.lda = Dm; pe1.ldb = Dm;
    gemm_bt<EPI_GELU_BF16, true, true>
        <<<dim3(DFFm / 128, Tm / 128, 4), dim3(256), 0, stream>>>(pe1);

    GemmP pe2{};
    pe2.Ah = HE; pe2.aBS = (long)Tm * DFFm;
    pe2.Bh = EW2T; pe2.bBS = (long)Dm * DFFm;
    pe2.bias = eb2 + (long)q * 4 * Dm; pe2.biasBS = Dm;
    pe2.rwp = rwout; pe2.cnt = cnt; pe2.idx = idxl; pe2.ebase = q * 4;
    pe2.outF = Y;
    pe2.K = 1024; pe2.N = Dm; pe2.lda = DFFm; pe2.ldb = DFFm;
    pe2.kcShift = 2; pe2.kcK = 1024;
    gemm_bt<EPI_MOE, false, true>
        <<<dim3(Dm / 128, Tm / 128, 16), dim3(256), 0, stream>>>(pe2);
  }

  // ---- final logits GEMM: 256^2 8-phase counted-vmcnt pipeline ----
  cvt_bf16_kernel<<<dim3(Tm * Dm / (256 * 8)), dim3(256), 0, stream>>>(Y, YB, (long)Tm * Dm);
  transpose_cvt<false><<<dim3(Vm / 64, Dm / 64, 1), dim3(16, 16), 0, stream>>>(
      Wl, WLT, Dm, Vm, 0, 0);
  gemm256_8p<true><<<dim3(Vm / 256, Tm / 256, 1), dim3(512), 0, stream>>>(
      YB, WLT, bl, logits, Dm, Vm);
}